// Round 10
// baseline (186.896 us; speedup 1.0000x reference)
//
#include <hip/hip_runtime.h>

#define NGRAPHS 2048
#define DIN     1536
#define DH1     64
#define DH2     32
#define POOL_BLOCKS 1280   // 5 blocks/CU x 256 CU — all co-resident, work-stealing

typedef float fvec4 __attribute__((ext_vector_type(4)));

// ---------------- Pass 1: segment offsets (batch sorted) + zero counter -----
__global__ void find_offsets_kernel(const int* __restrict__ batch, int n,
                                    int* __restrict__ offsets,
                                    int* __restrict__ counter) {
    int i = blockIdx.x * blockDim.x + threadIdx.x;
    if (i == 0) *counter = 0;                      // reset work queue every call
    if (i >= n) return;
    int b = batch[i];
    int prev = (i == 0) ? -1 : batch[i - 1];
    for (int g = prev + 1; g <= b; ++g) offsets[g] = i;
    if (i == n - 1) {
        for (int g = b + 1; g <= NGRAPHS; ++g) offsets[g] = n;
    }
}

// ---------------- Pass 2: persistent fused pool+MLP with work-stealing ------
// 1280 blocks x 384 threads (6 waves). Work-stealing equalizes finish times.
// A/B vs R6: plain cached loads instead of nontemporal — NT may route the
// stream around the faster cached-read path. Everything else identical.
__global__ __launch_bounds__(384) void pool_mlp_ws_kernel(
    const float* __restrict__ features,
    const int* __restrict__ offsets,
    const float* __restrict__ W1, const float* __restrict__ b1,
    const float* __restrict__ W2, const float* __restrict__ b2,
    const float* __restrict__ W3, const float* __restrict__ b3,
    float* __restrict__ out,
    int* __restrict__ counter)
{
    const int tid  = threadIdx.x;
    const int lane = tid & 63;
    const int wave = tid >> 6;

    __shared__ float mean_s[DIN];
    __shared__ float h1_s[DH1];
    __shared__ float h2_s[DH2];
    __shared__ int   g_s;

    const fvec4* __restrict__ F4 = reinterpret_cast<const fvec4*>(features);

    for (;;) {
        if (tid == 0) g_s = atomicAdd(counter, 1);
        __syncthreads();
        const int g = g_s;
        if (g >= NGRAPHS) break;

        const int s = offsets[g];
        const int e = offsets[g + 1];

        // ---- segment sum: coalesced stream, x4 row unroll ----
        fvec4 a0 = (fvec4)(0.f);
        fvec4 a1 = (fvec4)(0.f);
        fvec4 a2 = (fvec4)(0.f);
        fvec4 a3 = (fvec4)(0.f);
        int r = s;
        for (; r + 4 <= e; r += 4) {
            fvec4 v0 = F4[(size_t)(r + 0) * (DIN / 4) + tid];
            fvec4 v1 = F4[(size_t)(r + 1) * (DIN / 4) + tid];
            fvec4 v2 = F4[(size_t)(r + 2) * (DIN / 4) + tid];
            fvec4 v3 = F4[(size_t)(r + 3) * (DIN / 4) + tid];
            a0 += v0; a1 += v1; a2 += v2; a3 += v3;
        }
        for (; r < e; ++r) {
            a0 += F4[(size_t)r * (DIN / 4) + tid];
        }
        a0 += a1 + a2 + a3;

        const int cnt = e - s;
        const float inv = 1.0f / (float)(cnt > 1 ? cnt : 1);
        a0 *= inv;
        reinterpret_cast<fvec4*>(mean_s)[tid] = a0;
        __syncthreads();

        // ---- layer 1: wave-cooperative, coalesced W1 (hot in L2) ----
        const fvec4* __restrict__ m4 = reinterpret_cast<const fvec4*>(mean_s);
        for (int j = wave; j < DH1; j += 6) {
            const fvec4* __restrict__ w4 =
                reinterpret_cast<const fvec4*>(W1 + (size_t)j * DIN);
            float acc = 0.f;
            #pragma unroll
            for (int k = 0; k < DIN / 4 / 64; ++k) {      // 6 iters
                fvec4 w = w4[k * 64 + lane];
                fvec4 m = m4[k * 64 + lane];
                acc += m.x * w.x + m.y * w.y + m.z * w.z + m.w * w.w;
            }
            #pragma unroll
            for (int off = 32; off; off >>= 1) acc += __shfl_xor(acc, off, 64);
            if (lane == 0) h1_s[j] = fmaxf(acc + b1[j], 0.f);
        }
        __syncthreads();

        // ---- layer 2 ----
        for (int j = wave; j < DH2; j += 6) {
            float acc = h1_s[lane] * W2[(size_t)j * DH1 + lane];
            #pragma unroll
            for (int off = 32; off; off >>= 1) acc += __shfl_xor(acc, off, 64);
            if (lane == 0) h2_s[j] = fmaxf(acc + b2[j], 0.f);
        }
        __syncthreads();

        // ---- layer 3 ----
        if (wave == 0) {
            float acc = (lane < DH2) ? h2_s[lane] * W3[lane] : 0.f;
            #pragma unroll
            for (int off = 32; off; off >>= 1) acc += __shfl_xor(acc, off, 64);
            if (lane == 0) out[g] = acc + b3[0];
        }
        __syncthreads();   // protect g_s / mean_s / h*_s before next grab
    }
}

extern "C" void kernel_launch(void* const* d_in, const int* in_sizes, int n_in,
                              void* d_out, int out_size, void* d_ws, size_t ws_size,
                              hipStream_t stream) {
    const float* features = (const float*)d_in[0];
    const int*   batch    = (const int*)d_in[1];   // int64 in ref -> int32 (x64 off)
    const float* W1 = (const float*)d_in[2];
    const float* b1 = (const float*)d_in[3];
    const float* W2 = (const float*)d_in[4];
    const float* b2 = (const float*)d_in[5];
    const float* W3 = (const float*)d_in[6];
    const float* b3 = (const float*)d_in[7];
    float* out = (float*)d_out;

    const int n = in_sizes[1];                 // 131072 rows
    int* counter = (int*)d_ws;                 // [0]: work-queue counter
    int* offsets = (int*)d_ws + 64;            // (NGRAPHS+1) ints, 256B-aligned

    find_offsets_kernel<<<(n + 255) / 256, 256, 0, stream>>>(batch, n, offsets,
                                                             counter);
    pool_mlp_ws_kernel<<<POOL_BLOCKS, 384, 0, stream>>>(features, offsets,
                                                        W1, b1, W2, b2, W3, b3,
                                                        out, counter);
}

// Round 11
// 163.694 us; speedup vs baseline: 1.1417x; 1.1417x over previous
//
#include <hip/hip_runtime.h>

#define NGRAPHS 2048
#define DIN     1536
#define DH1     64
#define DH2     32
#define POOL_BLOCKS 512   // 2 blocks/CU: 4 steal-units/block — finer makespan quantization

typedef float fvec4 __attribute__((ext_vector_type(4)));

// ---------------- Pass 1: segment offsets (batch sorted) + zero counter -----
__global__ void find_offsets_kernel(const int* __restrict__ batch, int n,
                                    int* __restrict__ offsets,
                                    int* __restrict__ counter) {
    int i = blockIdx.x * blockDim.x + threadIdx.x;
    if (i == 0) *counter = 0;                      // reset work queue every call
    if (i >= n) return;
    int b = batch[i];
    int prev = (i == 0) ? -1 : batch[i - 1];
    for (int g = prev + 1; g <= b; ++g) offsets[g] = i;
    if (i == n - 1) {
        for (int g = b + 1; g <= NGRAPHS; ++g) offsets[g] = n;
    }
}

// ---------------- Pass 2: persistent fused pool+MLP with work-stealing ------
// 512 blocks x 384 threads (6 waves). Work-stealing + nontemporal stream
// (NT keeps the single-use features out of L2/L3 — R9 A/B: +24us without it).
__global__ __launch_bounds__(384) void pool_mlp_ws_kernel(
    const float* __restrict__ features,
    const int* __restrict__ offsets,
    const float* __restrict__ W1, const float* __restrict__ b1,
    const float* __restrict__ W2, const float* __restrict__ b2,
    const float* __restrict__ W3, const float* __restrict__ b3,
    float* __restrict__ out,
    int* __restrict__ counter)
{
    const int tid  = threadIdx.x;
    const int lane = tid & 63;
    const int wave = tid >> 6;

    __shared__ float mean_s[DIN];
    __shared__ float h1_s[DH1];
    __shared__ float h2_s[DH2];
    __shared__ int   g_s;

    const fvec4* __restrict__ F4 = reinterpret_cast<const fvec4*>(features);

    for (;;) {
        if (tid == 0) g_s = atomicAdd(counter, 1);
        __syncthreads();
        const int g = g_s;
        if (g >= NGRAPHS) break;

        const int s = offsets[g];
        const int e = offsets[g + 1];

        // ---- segment sum: coalesced stream, x4 row unroll, nontemporal ----
        fvec4 a0 = (fvec4)(0.f);
        fvec4 a1 = (fvec4)(0.f);
        fvec4 a2 = (fvec4)(0.f);
        fvec4 a3 = (fvec4)(0.f);
        int r = s;
        for (; r + 4 <= e; r += 4) {
            fvec4 v0 = __builtin_nontemporal_load(&F4[(size_t)(r + 0) * (DIN / 4) + tid]);
            fvec4 v1 = __builtin_nontemporal_load(&F4[(size_t)(r + 1) * (DIN / 4) + tid]);
            fvec4 v2 = __builtin_nontemporal_load(&F4[(size_t)(r + 2) * (DIN / 4) + tid]);
            fvec4 v3 = __builtin_nontemporal_load(&F4[(size_t)(r + 3) * (DIN / 4) + tid]);
            a0 += v0; a1 += v1; a2 += v2; a3 += v3;
        }
        for (; r < e; ++r) {
            a0 += __builtin_nontemporal_load(&F4[(size_t)r * (DIN / 4) + tid]);
        }
        a0 += a1 + a2 + a3;

        const int cnt = e - s;
        const float inv = 1.0f / (float)(cnt > 1 ? cnt : 1);
        a0 *= inv;
        reinterpret_cast<fvec4*>(mean_s)[tid] = a0;
        __syncthreads();

        // ---- layer 1: wave-cooperative, coalesced W1 (hot in L2) ----
        const fvec4* __restrict__ m4 = reinterpret_cast<const fvec4*>(mean_s);
        for (int j = wave; j < DH1; j += 6) {
            const fvec4* __restrict__ w4 =
                reinterpret_cast<const fvec4*>(W1 + (size_t)j * DIN);
            float acc = 0.f;
            #pragma unroll
            for (int k = 0; k < DIN / 4 / 64; ++k) {      // 6 iters
                fvec4 w = w4[k * 64 + lane];
                fvec4 m = m4[k * 64 + lane];
                acc += m.x * w.x + m.y * w.y + m.z * w.z + m.w * w.w;
            }
            #pragma unroll
            for (int off = 32; off; off >>= 1) acc += __shfl_xor(acc, off, 64);
            if (lane == 0) h1_s[j] = fmaxf(acc + b1[j], 0.f);
        }
        __syncthreads();

        // ---- layer 2 ----
        for (int j = wave; j < DH2; j += 6) {
            float acc = h1_s[lane] * W2[(size_t)j * DH1 + lane];
            #pragma unroll
            for (int off = 32; off; off >>= 1) acc += __shfl_xor(acc, off, 64);
            if (lane == 0) h2_s[j] = fmaxf(acc + b2[j], 0.f);
        }
        __syncthreads();

        // ---- layer 3 ----
        if (wave == 0) {
            float acc = (lane < DH2) ? h2_s[lane] * W3[lane] : 0.f;
            #pragma unroll
            for (int off = 32; off; off >>= 1) acc += __shfl_xor(acc, off, 64);
            if (lane == 0) out[g] = acc + b3[0];
        }
        __syncthreads();   // protect g_s / mean_s / h*_s before next grab
    }
}

extern "C" void kernel_launch(void* const* d_in, const int* in_sizes, int n_in,
                              void* d_out, int out_size, void* d_ws, size_t ws_size,
                              hipStream_t stream) {
    const float* features = (const float*)d_in[0];
    const int*   batch    = (const int*)d_in[1];   // int64 in ref -> int32 (x64 off)
    const float* W1 = (const float*)d_in[2];
    const float* b1 = (const float*)d_in[3];
    const float* W2 = (const float*)d_in[4];
    const float* b2 = (const float*)d_in[5];
    const float* W3 = (const float*)d_in[6];
    const float* b3 = (const float*)d_in[7];
    float* out = (float*)d_out;

    const int n = in_sizes[1];                 // 131072 rows
    int* counter = (int*)d_ws;                 // [0]: work-queue counter
    int* offsets = (int*)d_ws + 64;            // (NGRAPHS+1) ints, 256B-aligned

    find_offsets_kernel<<<(n + 255) / 256, 256, 0, stream>>>(batch, n, offsets,
                                                             counter);
    pool_mlp_ws_kernel<<<POOL_BLOCKS, 384, 0, stream>>>(features, offsets,
                                                        W1, b1, W2, b2, W3, b3,
                                                        out, counter);
}